// Round 7
// baseline (87.825 us; speedup 1.0000x reference)
//
#include <hip/hip_runtime.h>

#define NB 8
#define NT 2048
#define NC 1024
#define NH 64

typedef __bf16 bf16x8 __attribute__((ext_vector_type(8)));
typedef float f32x4 __attribute__((ext_vector_type(4)));

static __device__ __forceinline__ float4 ldf4(const float* p) {
  return *reinterpret_cast<const float4*>(p);
}
static __device__ __forceinline__ bf16x8 ldb8(const __bf16* p) {
  return *reinterpret_cast<const bf16x8*>(p);
}
static __device__ __forceinline__ unsigned pack_bf2(float a, float b) {
  unsigned short ua = __builtin_bit_cast(unsigned short, (__bf16)a);
  unsigned short ub = __builtin_bit_cast(unsigned short, (__bf16)b);
  return (unsigned)ua | ((unsigned)ub << 16);
}
static __device__ __forceinline__ bf16x8 cvt8(float4 a, float4 b) {
  bf16x8 r;
  r[0] = (__bf16)a.x; r[1] = (__bf16)a.y; r[2] = (__bf16)a.z; r[3] = (__bf16)a.w;
  r[4] = (__bf16)b.x; r[5] = (__bf16)b.y; r[6] = (__bf16)b.z; r[7] = (__bf16)b.w;
  return r;
}

// ---------------------------------------------------------------------------
// Kernel A: Wt[192][1024] bf16 = transpose+convert of Wq|Wk|Wv (fp32 [1024][64]).
// ---------------------------------------------------------------------------
__global__ __launch_bounds__(256) void wt_kernel(
    const float* __restrict__ Wq, const float* __restrict__ Wk,
    const float* __restrict__ Wv, __bf16* __restrict__ wt) {
  __shared__ __bf16 tl[64][72];
  const int tid = threadIdx.x;
  const int mat = blockIdx.x >> 4;
  const int k0 = (blockIdx.x & 15) * 64;
  const float* W = (mat == 0) ? Wq : (mat == 1) ? Wk : Wv;
#pragma unroll
  for (int it = 0; it < 4; ++it) {
    int f = tid + it * 256;
    int kk = f >> 4, c4 = (f & 15) * 4;
    float4 w = ldf4(&W[(k0 + kk) * NH + c4]);
    tl[c4 + 0][kk] = (__bf16)w.x;
    tl[c4 + 1][kk] = (__bf16)w.y;
    tl[c4 + 2][kk] = (__bf16)w.z;
    tl[c4 + 3][kk] = (__bf16)w.w;
  }
  __syncthreads();
#pragma unroll
  for (int it = 0; it < 2; ++it) {
    int f = tid + it * 256;
    int h = f >> 3, k8 = (f & 7) * 8;
    *reinterpret_cast<bf16x8*>(&wt[(mat * 64 + h) * NC + k0 + k8]) =
        *reinterpret_cast<const bf16x8*>(&tl[h][k8]);
  }
}

// ---------------------------------------------------------------------------
// Kernel B: q,k (bf16 row-major) and v^T (bf16 [b][h][t]) = x @ W via MFMA.
// BARRIER-FREE STREAMING: no LDS staging in the main loop. Both MFMA operand
// fragments are contiguous 16B per lane in global memory:
//   A-frag: 8 consecutive fp32 of one x row (cvt to bf16 in regs),
//   B-frag: 16B octet of wt[col][k] (L2-resident, 384 KB).
// 512 blocks x 256 thr = 4 waves; wave (wr=w>>1, wc=w&1) owns rows
// row0+wr*16+[0,16) x cols wc*96+[0,96). K-loop 32 steps, fully unrolled,
// 1-deep register double buffer (load k+1 overlaps 6 MFMAs of k).
// 8 free-running waves/CU: latency hidden by ILP+TLP, zero barriers.
// ---------------------------------------------------------------------------
__global__ __launch_bounds__(256, 2) void qkv_mfma_kernel(
    const float* __restrict__ x, const __bf16* __restrict__ wt,
    __bf16* __restrict__ qb, __bf16* __restrict__ kb, __bf16* __restrict__ vt) {
  __shared__ __bf16 vls[64][40];   // [h][t_local] for v transpose epilogue
  const int tid = threadIdx.x;
  const int lane = tid & 63;
  const int w = tid >> 6;          // 0..3
  const int wr = w >> 1, wc = w & 1;
  const int row0 = blockIdx.x * 32;
  const int l15 = lane & 15, lg = lane >> 4;

  f32x4 acc[6];
#pragma unroll
  for (int j = 0; j < 6; ++j) acc[j] = (f32x4){0.f, 0.f, 0.f, 0.f};

  // per-lane base pointers
  const float* xr = &x[(size_t)(row0 + wr * 16 + l15) * NC + lg * 8];
  const __bf16* wb = &wt[(size_t)(wc * 96 + l15) * NC + lg * 8];

  float4 a0 = ldf4(xr), a1 = ldf4(xr + 4);
  bf16x8 b[6];
#pragma unroll
  for (int nt = 0; nt < 6; ++nt) b[nt] = ldb8(wb + nt * 16 * NC);

#pragma unroll
  for (int ks = 0; ks < 32; ++ks) {
    float4 a0n, a1n;
    bf16x8 bn[6];
    if (ks < 31) {
      const int off = (ks + 1) * 32;
      a0n = ldf4(xr + off);
      a1n = ldf4(xr + off + 4);
#pragma unroll
      for (int nt = 0; nt < 6; ++nt) bn[nt] = ldb8(wb + nt * 16 * NC + off);
    }
    bf16x8 af = cvt8(a0, a1);
#pragma unroll
    for (int nt = 0; nt < 6; ++nt)
      acc[nt] = __builtin_amdgcn_mfma_f32_16x16x32_bf16(af, b[nt], acc[nt], 0, 0, 0);
    if (ks < 31) {
      a0 = a0n; a1 = a1n;
#pragma unroll
      for (int nt = 0; nt < 6; ++nt) b[nt] = bn[nt];
    }
  }

  // epilogue: D layout col=l15, row=lg*4+r. mat uniform per (wc,nt).
#pragma unroll
  for (int nt = 0; nt < 6; ++nt) {
    const int colbase = wc * 96 + nt * 16;   // wave-uniform, multiple of 16
    const int mat = colbase >> 6;
    if (mat == 0) {
      const int h = (colbase & 63) + l15;
#pragma unroll
      for (int r = 0; r < 4; ++r) {
        int row = row0 + wr * 16 + lg * 4 + r;
        qb[row * NH + h] = (__bf16)(acc[nt][r] * 0.125f);  // pre-scale q
      }
    } else if (mat == 1) {
      const int h = (colbase & 63) + l15;
#pragma unroll
      for (int r = 0; r < 4; ++r) {
        int row = row0 + wr * 16 + lg * 4 + r;
        kb[row * NH + h] = (__bf16)acc[nt][r];
      }
    } else {
      // v: stage transposed into LDS (4 consecutive t = one 8B write)
      const int h = (colbase - 128) + l15;
      ushort4 pk;
      pk.x = __builtin_bit_cast(unsigned short, (__bf16)acc[nt][0]);
      pk.y = __builtin_bit_cast(unsigned short, (__bf16)acc[nt][1]);
      pk.z = __builtin_bit_cast(unsigned short, (__bf16)acc[nt][2]);
      pk.w = __builtin_bit_cast(unsigned short, (__bf16)acc[nt][3]);
      *reinterpret_cast<ushort4*>(&vls[h][wr * 16 + lg * 4]) = pk;
    }
  }
  __syncthreads();
  // cooperative coalesced v^T store: 64 h x 32 t, one 16B store per thread
  {
    int h = tid >> 2, t8 = (tid & 3) * 8;
    int bb = row0 >> 11;
    int t0l = row0 & (NT - 1);
    *reinterpret_cast<bf16x8*>(&vt[((size_t)bb * NH + h) * NT + t0l + t8]) =
        *reinterpret_cast<const bf16x8*>(&vls[h][t8]);
  }
}

// ---------------------------------------------------------------------------
// Kernel C: causal flash attention via MFMA, intra-block KV split.
// (exact R4 version, 48.1 us config) Grid dim3(64,8); qt = (y<4) ? 63-x : x
// so the two blocks sharing a CU have complementary work. 256 thr = 4 waves;
// wave w handles KV chunks c = w, w+4, ... setprio(1) around MFMA clusters.
// ---------------------------------------------------------------------------
__global__ __launch_bounds__(256, 2) void attn_mfma_kernel(
    const __bf16* __restrict__ qb, const __bf16* __restrict__ kb,
    const __bf16* __restrict__ vt, float* __restrict__ out) {
  __shared__ __bf16 ps[4][32][72];   // per-wave P tile [qrow][s]
  __shared__ float obuf[4][32][68];  // per-wave O partial
  __shared__ float msh[4][32], lsh[4][32];
  const int tid = threadIdx.x;
  const int lane = tid & 63;
  const int w = tid >> 6;
  const int l15 = lane & 15, lg = lane >> 4;
  const int b = blockIdx.y;
  const int qt = (blockIdx.y < 4) ? (63 - (int)blockIdx.x) : (int)blockIdx.x;
  const int q0 = qt * 32;
  const size_t bT = (size_t)b * NT;

  bf16x8 qf[2][2];
#pragma unroll
  for (int ct = 0; ct < 2; ++ct)
#pragma unroll
    for (int kh = 0; kh < 2; ++kh)
      qf[ct][kh] = *reinterpret_cast<const bf16x8*>(
          &qb[(bT + q0 + ct * 16 + l15) * NH + kh * 32 + lg * 8]);

  float m[2] = {-1e30f, -1e30f};
  float lsum[2] = {0.f, 0.f};
  f32x4 o[2][4];
#pragma unroll
  for (int i = 0; i < 2; ++i)
#pragma unroll
    for (int j = 0; j < 4; ++j) o[i][j] = (f32x4){0.f, 0.f, 0.f, 0.f};

  const int nch = qt / 2 + 1;
  bf16x8 kf[4][2], vf[4][2];
  if (w < nch) {
    const int s0 = w * 64;
#pragma unroll
    for (int st = 0; st < 4; ++st)
#pragma unroll
      for (int kh = 0; kh < 2; ++kh)
        kf[st][kh] = *reinterpret_cast<const bf16x8*>(
            &kb[(bT + s0 + st * 16 + l15) * NH + kh * 32 + lg * 8]);
#pragma unroll
    for (int ht = 0; ht < 4; ++ht)
#pragma unroll
      for (int sh = 0; sh < 2; ++sh)
        vf[ht][sh] = *reinterpret_cast<const bf16x8*>(
            &vt[((size_t)b * NH + ht * 16 + l15) * NT + s0 + sh * 32 + lg * 8]);
  }

  for (int c = w; c < nch; c += 4) {
    const int s0 = c * 64;
    f32x4 s[4][2];
#pragma unroll
    for (int st = 0; st < 4; ++st)
#pragma unroll
      for (int ct = 0; ct < 2; ++ct) s[st][ct] = (f32x4){0.f, 0.f, 0.f, 0.f};
    __builtin_amdgcn_s_setprio(1);
#pragma unroll
    for (int st = 0; st < 4; ++st)
#pragma unroll
      for (int ct = 0; ct < 2; ++ct)
#pragma unroll
        for (int kh = 0; kh < 2; ++kh)
          s[st][ct] = __builtin_amdgcn_mfma_f32_16x16x32_bf16(kf[st][kh], qf[ct][kh], s[st][ct], 0, 0, 0);
    __builtin_amdgcn_s_setprio(0);

    const int cn = c + 4;
    bf16x8 kfn[4][2], vfn[4][2];
    if (cn < nch) {
      const int sn = cn * 64;
#pragma unroll
      for (int st = 0; st < 4; ++st)
#pragma unroll
        for (int kh = 0; kh < 2; ++kh)
          kfn[st][kh] = *reinterpret_cast<const bf16x8*>(
              &kb[(bT + sn + st * 16 + l15) * NH + kh * 32 + lg * 8]);
#pragma unroll
      for (int ht = 0; ht < 4; ++ht)
#pragma unroll
        for (int sh = 0; sh < 2; ++sh)
          vfn[ht][sh] = *reinterpret_cast<const bf16x8*>(
              &vt[((size_t)b * NH + ht * 16 + l15) * NT + sn + sh * 32 + lg * 8]);
    }

    if (s0 + 63 > q0) {
#pragma unroll
      for (int st = 0; st < 4; ++st)
#pragma unroll
        for (int ct = 0; ct < 2; ++ct) {
          int qg = q0 + ct * 16 + l15;
#pragma unroll
          for (int r = 0; r < 4; ++r) {
            int sg = s0 + st * 16 + lg * 4 + r;
            if (sg > qg) s[st][ct][r] = -1e30f;
          }
        }
    }
    float scv[2];
#pragma unroll
    for (int ct = 0; ct < 2; ++ct) {
      float rmx = -1e30f;
#pragma unroll
      for (int st = 0; st < 4; ++st)
#pragma unroll
        for (int r = 0; r < 4; ++r) rmx = fmaxf(rmx, s[st][ct][r]);
      rmx = fmaxf(rmx, __shfl_xor(rmx, 16));
      rmx = fmaxf(rmx, __shfl_xor(rmx, 32));
      float mn = fmaxf(m[ct], rmx);
      float sc = __expf(m[ct] - mn);
      m[ct] = mn;
      float rs = 0.f;
#pragma unroll
      for (int st = 0; st < 4; ++st) {
        float p0 = __expf(s[st][ct][0] - mn);
        float p1 = __expf(s[st][ct][1] - mn);
        float p2 = __expf(s[st][ct][2] - mn);
        float p3 = __expf(s[st][ct][3] - mn);
        rs += (p0 + p1) + (p2 + p3);
        int sp = st * 16 + lg * 4;
        *reinterpret_cast<unsigned*>(&ps[w][ct * 16 + l15][sp]) = pack_bf2(p0, p1);
        *reinterpret_cast<unsigned*>(&ps[w][ct * 16 + l15][sp + 2]) = pack_bf2(p2, p3);
      }
      rs += __shfl_xor(rs, 16);
      rs += __shfl_xor(rs, 32);
      lsum[ct] = lsum[ct] * sc + rs;
      scv[ct] = sc;
    }
#pragma unroll
    for (int rt = 0; rt < 2; ++rt)
#pragma unroll
      for (int r = 0; r < 4; ++r) {
        float fsc = __shfl(scv[rt], lg * 4 + r, 64);
#pragma unroll
        for (int ht = 0; ht < 4; ++ht) o[rt][ht][r] *= fsc;
      }
    __builtin_amdgcn_s_setprio(1);
#pragma unroll
    for (int rt = 0; rt < 2; ++rt) {
      bf16x8 pf[2];
#pragma unroll
      for (int sh = 0; sh < 2; ++sh)
        pf[sh] = *reinterpret_cast<const bf16x8*>(&ps[w][rt * 16 + l15][sh * 32 + lg * 8]);
#pragma unroll
      for (int ht = 0; ht < 4; ++ht)
#pragma unroll
        for (int sh = 0; sh < 2; ++sh)
          o[rt][ht] = __builtin_amdgcn_mfma_f32_16x16x32_bf16(pf[sh], vf[ht][sh], o[rt][ht], 0, 0, 0);
    }
    __builtin_amdgcn_s_setprio(0);
    if (cn < nch) {
#pragma unroll
      for (int st = 0; st < 4; ++st)
#pragma unroll
        for (int kh = 0; kh < 2; ++kh) kf[st][kh] = kfn[st][kh];
#pragma unroll
      for (int ht = 0; ht < 4; ++ht)
#pragma unroll
        for (int sh = 0; sh < 2; ++sh) vf[ht][sh] = vfn[ht][sh];
    }
  }

  if (lg == 0) {
#pragma unroll
    for (int ct = 0; ct < 2; ++ct) {
      msh[w][ct * 16 + l15] = m[ct];
      lsh[w][ct * 16 + l15] = lsum[ct];
    }
  }
#pragma unroll
  for (int rt = 0; rt < 2; ++rt)
#pragma unroll
    for (int ht = 0; ht < 4; ++ht)
#pragma unroll
      for (int r = 0; r < 4; ++r)
        obuf[w][rt * 16 + lg * 4 + r][ht * 16 + l15] = o[rt][ht][r];
  __syncthreads();

  {
    int qr = tid >> 3, h8 = (tid & 7) * 8;
    float m0 = msh[0][qr], m1 = msh[1][qr], m2 = msh[2][qr], m3 = msh[3][qr];
    float M = fmaxf(fmaxf(m0, m1), fmaxf(m2, m3));
    float e0 = __expf(m0 - M), e1 = __expf(m1 - M);
    float e2 = __expf(m2 - M), e3 = __expf(m3 - M);
    float L = e0 * lsh[0][qr] + e1 * lsh[1][qr] + e2 * lsh[2][qr] + e3 * lsh[3][qr];
    float inv = 1.f / L;
#pragma unroll
    for (int i = 0; i < 8; ++i) {
      int h = h8 + i;
      float v = e0 * obuf[0][qr][h] + e1 * obuf[1][qr][h] +
                e2 * obuf[2][qr][h] + e3 * obuf[3][qr][h];
      out[(bT + q0 + qr) * NH + h] = v * inv;
    }
  }
}

extern "C" void kernel_launch(void* const* d_in, const int* in_sizes, int n_in,
                              void* d_out, int out_size, void* d_ws, size_t ws_size,
                              hipStream_t stream) {
  const float* x  = (const float*)d_in[0];
  const float* Wq = (const float*)d_in[1];
  const float* Wk = (const float*)d_in[2];
  const float* Wv = (const float*)d_in[3];
  float* out = (float*)d_out;

  char* ws = (char*)d_ws;
  __bf16* wt = (__bf16*)(ws);                        // 192*1024*2 = 384 KB
  __bf16* qb = (__bf16*)(ws + 393216);               // 2 MB
  __bf16* kb = (__bf16*)(ws + 393216 + 2097152);     // 2 MB
  __bf16* vt = (__bf16*)(ws + 393216 + 2 * 2097152); // 2 MB  (total ~6.7 MB)

  wt_kernel<<<dim3(48), dim3(256), 0, stream>>>(Wq, Wk, Wv, wt);
  qkv_mfma_kernel<<<dim3(512), dim3(256), 0, stream>>>(x, wt, qb, kb, vt);
  attn_mfma_kernel<<<dim3(64, 8), dim3(256), 0, stream>>>(qb, kb, vt, out);
}

// Round 8
// 56.619 us; speedup vs baseline: 1.5512x; 1.5512x over previous
//
#include <hip/hip_runtime.h>

#define NB 8
#define NT 2048
#define NC 1024
#define NH 64

typedef __bf16 bf16x8 __attribute__((ext_vector_type(8)));
typedef float f32x4 __attribute__((ext_vector_type(4)));

static __device__ __forceinline__ float4 ldf4(const float* p) {
  return *reinterpret_cast<const float4*>(p);
}
static __device__ __forceinline__ bf16x8 ldb8(const __bf16* p) {
  return *reinterpret_cast<const bf16x8*>(p);
}
static __device__ __forceinline__ unsigned pack_bf2(float a, float b) {
  unsigned short ua = __builtin_bit_cast(unsigned short, (__bf16)a);
  unsigned short ub = __builtin_bit_cast(unsigned short, (__bf16)b);
  return (unsigned)ua | ((unsigned)ub << 16);
}
static __device__ __forceinline__ bf16x8 cvt8(float4 a, float4 b) {
  bf16x8 r;
  r[0] = (__bf16)a.x; r[1] = (__bf16)a.y; r[2] = (__bf16)a.z; r[3] = (__bf16)a.w;
  r[4] = (__bf16)b.x; r[5] = (__bf16)b.y; r[6] = (__bf16)b.z; r[7] = (__bf16)b.w;
  return r;
}
// async global->LDS DMA, 16B/lane: LDS dest = wave-uniform base + lane*16
static __device__ __forceinline__ void gload16f(const float* g, float* l) {
  __builtin_amdgcn_global_load_lds(
      (const __attribute__((address_space(1))) unsigned int*)g,
      (__attribute__((address_space(3))) unsigned int*)l, 16, 0, 0);
}

// ---------------------------------------------------------------------------
// Kernel A: Wt[192][1024] bf16 = transpose+convert of Wq|Wk|Wv (fp32 [1024][64]).
// ---------------------------------------------------------------------------
__global__ __launch_bounds__(256) void wt_kernel(
    const float* __restrict__ Wq, const float* __restrict__ Wk,
    const float* __restrict__ Wv, __bf16* __restrict__ wt) {
  __shared__ __bf16 tl[64][72];
  const int tid = threadIdx.x;
  const int mat = blockIdx.x >> 4;
  const int k0 = (blockIdx.x & 15) * 64;
  const float* W = (mat == 0) ? Wq : (mat == 1) ? Wk : Wv;
#pragma unroll
  for (int it = 0; it < 4; ++it) {
    int f = tid + it * 256;
    int kk = f >> 4, c4 = (f & 15) * 4;
    float4 w = ldf4(&W[(k0 + kk) * NH + c4]);
    tl[c4 + 0][kk] = (__bf16)w.x;
    tl[c4 + 1][kk] = (__bf16)w.y;
    tl[c4 + 2][kk] = (__bf16)w.z;
    tl[c4 + 3][kk] = (__bf16)w.w;
  }
  __syncthreads();
#pragma unroll
  for (int it = 0; it < 2; ++it) {
    int f = tid + it * 256;
    int h = f >> 3, k8 = (f & 7) * 8;
    *reinterpret_cast<bf16x8*>(&wt[(mat * 64 + h) * NC + k0 + k8]) =
        *reinterpret_cast<const bf16x8*>(&tl[h][k8]);
  }
}

// ---------------------------------------------------------------------------
// Kernel B: q,k (bf16 row-major) and v^T (bf16 [b][h][t]) = x @ W via MFMA.
// BM=32, BN=192, BK=64; 512 blocks x 256 thr (4 waves), 2 blocks/CU.
// COUNTED-VMCNT PIPELINE (T3/T4): per chunk issue {2 A-DMA + 6 B-reg loads}
// for chunk t+1, then s_waitcnt vmcnt(8) (NOT 0) + s_barrier, then compute t.
// The 8 newest vmem ops stay in flight across the barrier.
// A staged as fp32 via global_load_lds into As[2][32][64] (linear dest);
// bank conflicts on the fragment read fixed by quad-XOR applied to BOTH the
// global source (pre-swizzle) and the ds_read address (rule 21 involution).
// B (wt, L2-resident) prefetched to registers 1 chunk ahead.
// ---------------------------------------------------------------------------
__global__ __launch_bounds__(256, 2) void qkv_mfma_kernel(
    const float* __restrict__ x, const __bf16* __restrict__ wt,
    __bf16* __restrict__ qb, __bf16* __restrict__ kb, __bf16* __restrict__ vt) {
  __shared__ float As[2][32][64];  // 16 KB, DMA dest (linear, swizzled source)
  __shared__ __bf16 vls[64][40];   // v transpose epilogue
  const int tid = threadIdx.x;
  const int lane = tid & 63;
  const int w = tid >> 6;          // 0..3
  const int row0 = blockIdx.x * 32;
  const int csub = w * 48;
  const int l15 = lane & 15, lg = lane >> 4;

  f32x4 acc[2][3];
#pragma unroll
  for (int i = 0; i < 2; ++i)
#pragma unroll
    for (int j = 0; j < 3; ++j) acc[i][j] = (f32x4){0.f, 0.f, 0.f, 0.f};

  // A-DMA per-lane swizzled sources: it in {0,1}, f = it*256+tid,
  // row = f>>4, quad = f&15, src quad' = quad ^ (row&15)
  const int fr0 = tid >> 4, fq0 = tid & 15;
  const int fr1 = (tid + 256) >> 4, fq1 = (tid + 256) & 15;
  const float* xs0 = &x[(size_t)(row0 + fr0) * NC + ((fq0 ^ (fr0 & 15)) * 4)];
  const float* xs1 = &x[(size_t)(row0 + fr1) * NC + ((fq1 ^ (fr1 & 15)) * 4)];
  const int wuni = w * 256;  // wave-uniform LDS float offset (lane*4 implicit)

  // B per-lane base pointers: col = csub + nt*16 + l15, k-octet base lg*8
  const __bf16* wb0 = &wt[(size_t)(csub + l15) * NC + lg * 8];
  const __bf16* wb1 = wb0 + 16 * NC;
  const __bf16* wb2 = wb0 + 32 * NC;

  bf16x8 b00, b01, b10, b11, b20, b21;   // b[nt][kk] current
  bf16x8 n00, n01, n10, n11, n20, n21;   // next

  // prologue: stage chunk 0 (A-DMA + B-regs) -> 8 outstanding
  gload16f(xs0, &As[0][0][0] + wuni);
  gload16f(xs1, &As[0][0][0] + 1024 + wuni);
  b00 = ldb8(wb0); b01 = ldb8(wb0 + 32);
  b10 = ldb8(wb1); b11 = ldb8(wb1 + 32);
  b20 = ldb8(wb2); b21 = ldb8(wb2 + 32);

  for (int ch = 0; ch < 16; ++ch) {
    const int cur = ch & 1;
    __builtin_amdgcn_s_barrier();           // all waves done reading As[1-cur]
    // issue chunk ch+1 staging (clamped at the tail; redundant but harmless)
    const int chn = (ch < 15) ? ch + 1 : 15;
    const int offn = chn * 64;
    float* ad = &As[1 - cur][0][0];
    gload16f(xs0 + offn, ad + wuni);
    gload16f(xs1 + offn, ad + 1024 + wuni);
    n00 = ldb8(wb0 + offn); n01 = ldb8(wb0 + offn + 32);
    n10 = ldb8(wb1 + offn); n11 = ldb8(wb1 + offn + 32);
    n20 = ldb8(wb2 + offn); n21 = ldb8(wb2 + offn + 32);
    // wait for chunk ch's staging only: the 8 just-issued ops stay in flight
    asm volatile("s_waitcnt vmcnt(8)" ::: "memory");
    __builtin_amdgcn_sched_barrier(0);
    __builtin_amdgcn_s_barrier();           // As[cur] fully written (all waves)
    // compute chunk ch
#pragma unroll
    for (int kk = 0; kk < 2; ++kk) {
      bf16x8 af[2];
#pragma unroll
      for (int rt = 0; rt < 2; ++rt) {
        const int row = rt * 16 + l15;
        const int g = kk * 8 + lg * 2;
        float4 p0 = *reinterpret_cast<const float4*>(&As[cur][row][(g ^ l15) * 4]);
        float4 p1 = *reinterpret_cast<const float4*>(&As[cur][row][((g + 1) ^ l15) * 4]);
        af[rt] = cvt8(p0, p1);
      }
      const bf16x8 bk0 = kk ? b01 : b00;
      const bf16x8 bk1 = kk ? b11 : b10;
      const bf16x8 bk2 = kk ? b21 : b20;
#pragma unroll
      for (int rt = 0; rt < 2; ++rt) {
        acc[rt][0] = __builtin_amdgcn_mfma_f32_16x16x32_bf16(af[rt], bk0, acc[rt][0], 0, 0, 0);
        acc[rt][1] = __builtin_amdgcn_mfma_f32_16x16x32_bf16(af[rt], bk1, acc[rt][1], 0, 0, 0);
        acc[rt][2] = __builtin_amdgcn_mfma_f32_16x16x32_bf16(af[rt], bk2, acc[rt][2], 0, 0, 0);
      }
    }
    // rotate prefetched B regs in
    b00 = n00; b01 = n01; b10 = n10; b11 = n11; b20 = n20; b21 = n21;
  }

  // epilogue: D layout col=l15, row=lg*4+r. mat uniform per (w,nt).
#pragma unroll
  for (int rt = 0; rt < 2; ++rt) {
#pragma unroll
    for (int nt = 0; nt < 3; ++nt) {
      const int colbase = csub + nt * 16;   // wave-uniform, multiple of 16
      const int mat = colbase >> 6;
      const int h = (colbase & 63) + l15;
      if (mat == 0) {
#pragma unroll
        for (int r = 0; r < 4; ++r) {
          int row = row0 + rt * 16 + lg * 4 + r;
          qb[row * NH + h] = (__bf16)(acc[rt][nt][r] * 0.125f);  // pre-scale q
        }
      } else if (mat == 1) {
#pragma unroll
        for (int r = 0; r < 4; ++r) {
          int row = row0 + rt * 16 + lg * 4 + r;
          kb[row * NH + h] = (__bf16)acc[rt][nt][r];
        }
      } else {
        ushort4 pk;
        pk.x = __builtin_bit_cast(unsigned short, (__bf16)acc[rt][nt][0]);
        pk.y = __builtin_bit_cast(unsigned short, (__bf16)acc[rt][nt][1]);
        pk.z = __builtin_bit_cast(unsigned short, (__bf16)acc[rt][nt][2]);
        pk.w = __builtin_bit_cast(unsigned short, (__bf16)acc[rt][nt][3]);
        *reinterpret_cast<ushort4*>(&vls[h][rt * 16 + lg * 4]) = pk;
      }
    }
  }
  __syncthreads();
  // cooperative coalesced v^T store: 64 h x 32 t, one 16B store per thread
  {
    int h = tid >> 2, t8 = (tid & 3) * 8;
    int bb = row0 >> 11;
    int t0l = row0 & (NT - 1);
    *reinterpret_cast<bf16x8*>(&vt[((size_t)bb * NH + h) * NT + t0l + t8]) =
        *reinterpret_cast<const bf16x8*>(&vls[h][t8]);
  }
}

// ---------------------------------------------------------------------------
// Kernel C: causal flash attention via MFMA, intra-block KV split.
// (exact R4 version) Grid dim3(64,8); qt = (y<4) ? 63-x : x. 4 waves;
// wave w handles KV chunks c = w, w+4, ... setprio(1) around MFMA clusters.
// ---------------------------------------------------------------------------
__global__ __launch_bounds__(256, 2) void attn_mfma_kernel(
    const __bf16* __restrict__ qb, const __bf16* __restrict__ kb,
    const __bf16* __restrict__ vt, float* __restrict__ out) {
  __shared__ __bf16 ps[4][32][72];
  __shared__ float obuf[4][32][68];
  __shared__ float msh[4][32], lsh[4][32];
  const int tid = threadIdx.x;
  const int lane = tid & 63;
  const int w = tid >> 6;
  const int l15 = lane & 15, lg = lane >> 4;
  const int b = blockIdx.y;
  const int qt = (blockIdx.y < 4) ? (63 - (int)blockIdx.x) : (int)blockIdx.x;
  const int q0 = qt * 32;
  const size_t bT = (size_t)b * NT;

  bf16x8 qf[2][2];
#pragma unroll
  for (int ct = 0; ct < 2; ++ct)
#pragma unroll
    for (int kh = 0; kh < 2; ++kh)
      qf[ct][kh] = *reinterpret_cast<const bf16x8*>(
          &qb[(bT + q0 + ct * 16 + l15) * NH + kh * 32 + lg * 8]);

  float m[2] = {-1e30f, -1e30f};
  float lsum[2] = {0.f, 0.f};
  f32x4 o[2][4];
#pragma unroll
  for (int i = 0; i < 2; ++i)
#pragma unroll
    for (int j = 0; j < 4; ++j) o[i][j] = (f32x4){0.f, 0.f, 0.f, 0.f};

  const int nch = qt / 2 + 1;
  bf16x8 kf[4][2], vf[4][2];
  if (w < nch) {
    const int s0 = w * 64;
#pragma unroll
    for (int st = 0; st < 4; ++st)
#pragma unroll
      for (int kh = 0; kh < 2; ++kh)
        kf[st][kh] = *reinterpret_cast<const bf16x8*>(
            &kb[(bT + s0 + st * 16 + l15) * NH + kh * 32 + lg * 8]);
#pragma unroll
    for (int ht = 0; ht < 4; ++ht)
#pragma unroll
      for (int sh = 0; sh < 2; ++sh)
        vf[ht][sh] = *reinterpret_cast<const bf16x8*>(
            &vt[((size_t)b * NH + ht * 16 + l15) * NT + s0 + sh * 32 + lg * 8]);
  }

  for (int c = w; c < nch; c += 4) {
    const int s0 = c * 64;
    f32x4 s[4][2];
#pragma unroll
    for (int st = 0; st < 4; ++st)
#pragma unroll
      for (int ct = 0; ct < 2; ++ct) s[st][ct] = (f32x4){0.f, 0.f, 0.f, 0.f};
    __builtin_amdgcn_s_setprio(1);
#pragma unroll
    for (int st = 0; st < 4; ++st)
#pragma unroll
      for (int ct = 0; ct < 2; ++ct)
#pragma unroll
        for (int kh = 0; kh < 2; ++kh)
          s[st][ct] = __builtin_amdgcn_mfma_f32_16x16x32_bf16(kf[st][kh], qf[ct][kh], s[st][ct], 0, 0, 0);
    __builtin_amdgcn_s_setprio(0);

    const int cn = c + 4;
    bf16x8 kfn[4][2], vfn[4][2];
    if (cn < nch) {
      const int sn = cn * 64;
#pragma unroll
      for (int st = 0; st < 4; ++st)
#pragma unroll
        for (int kh = 0; kh < 2; ++kh)
          kfn[st][kh] = *reinterpret_cast<const bf16x8*>(
              &kb[(bT + sn + st * 16 + l15) * NH + kh * 32 + lg * 8]);
#pragma unroll
      for (int ht = 0; ht < 4; ++ht)
#pragma unroll
        for (int sh = 0; sh < 2; ++sh)
          vfn[ht][sh] = *reinterpret_cast<const bf16x8*>(
              &vt[((size_t)b * NH + ht * 16 + l15) * NT + sn + sh * 32 + lg * 8]);
    }

    if (s0 + 63 > q0) {
#pragma unroll
      for (int st = 0; st < 4; ++st)
#pragma unroll
        for (int ct = 0; ct < 2; ++ct) {
          int qg = q0 + ct * 16 + l15;
#pragma unroll
          for (int r = 0; r < 4; ++r) {
            int sg = s0 + st * 16 + lg * 4 + r;
            if (sg > qg) s[st][ct][r] = -1e30f;
          }
        }
    }
    float scv[2];
#pragma unroll
    for (int ct = 0; ct < 2; ++ct) {
      float rmx = -1e30f;
#pragma unroll
      for (int st = 0; st < 4; ++st)
#pragma unroll
        for (int r = 0; r < 4; ++r) rmx = fmaxf(rmx, s[st][ct][r]);
      rmx = fmaxf(rmx, __shfl_xor(rmx, 16));
      rmx = fmaxf(rmx, __shfl_xor(rmx, 32));
      float mn = fmaxf(m[ct], rmx);
      float sc = __expf(m[ct] - mn);
      m[ct] = mn;
      float rs = 0.f;
#pragma unroll
      for (int st = 0; st < 4; ++st) {
        float p0 = __expf(s[st][ct][0] - mn);
        float p1 = __expf(s[st][ct][1] - mn);
        float p2 = __expf(s[st][ct][2] - mn);
        float p3 = __expf(s[st][ct][3] - mn);
        rs += (p0 + p1) + (p2 + p3);
        int sp = st * 16 + lg * 4;
        *reinterpret_cast<unsigned*>(&ps[w][ct * 16 + l15][sp]) = pack_bf2(p0, p1);
        *reinterpret_cast<unsigned*>(&ps[w][ct * 16 + l15][sp + 2]) = pack_bf2(p2, p3);
      }
      rs += __shfl_xor(rs, 16);
      rs += __shfl_xor(rs, 32);
      lsum[ct] = lsum[ct] * sc + rs;
      scv[ct] = sc;
    }
#pragma unroll
    for (int rt = 0; rt < 2; ++rt)
#pragma unroll
      for (int r = 0; r < 4; ++r) {
        float fsc = __shfl(scv[rt], lg * 4 + r, 64);
#pragma unroll
        for (int ht = 0; ht < 4; ++ht) o[rt][ht][r] *= fsc;
      }
    __builtin_amdgcn_s_setprio(1);
#pragma unroll
    for (int rt = 0; rt < 2; ++rt) {
      bf16x8 pf[2];
#pragma unroll
      for (int sh = 0; sh < 2; ++sh)
        pf[sh] = *reinterpret_cast<const bf16x8*>(&ps[w][rt * 16 + l15][sh * 32 + lg * 8]);
#pragma unroll
      for (int ht = 0; ht < 4; ++ht)
#pragma unroll
        for (int sh = 0; sh < 2; ++sh)
          o[rt][ht] = __builtin_amdgcn_mfma_f32_16x16x32_bf16(pf[sh], vf[ht][sh], o[rt][ht], 0, 0, 0);
    }
    __builtin_amdgcn_s_setprio(0);
    if (cn < nch) {
#pragma unroll
      for (int st = 0; st < 4; ++st)
#pragma unroll
        for (int kh = 0; kh < 2; ++kh) kf[st][kh] = kfn[st][kh];
#pragma unroll
      for (int ht = 0; ht < 4; ++ht)
#pragma unroll
        for (int sh = 0; sh < 2; ++sh) vf[ht][sh] = vfn[ht][sh];
    }
  }

  if (lg == 0) {
#pragma unroll
    for (int ct = 0; ct < 2; ++ct) {
      msh[w][ct * 16 + l15] = m[ct];
      lsh[w][ct * 16 + l15] = lsum[ct];
    }
  }
#pragma unroll
  for (int rt = 0; rt < 2; ++rt)
#pragma unroll
    for (int ht = 0; ht < 4; ++ht)
#pragma unroll
      for (int r = 0; r < 4; ++r)
        obuf[w][rt * 16 + lg * 4 + r][ht * 16 + l15] = o[rt][ht][r];
  __syncthreads();

  {
    int qr = tid >> 3, h8 = (tid & 7) * 8;
    float m0 = msh[0][qr], m1 = msh[1][qr], m2 = msh[2][qr], m3 = msh[3][qr];
    float M = fmaxf(fmaxf(m0, m1), fmaxf(m2, m3));
    float e0 = __expf(m0 - M), e1 = __expf(m1 - M);
    float e2 = __expf(m2 - M), e3 = __expf(m3 - M);
    float L = e0 * lsh[0][qr] + e1 * lsh[1][qr] + e2 * lsh[2][qr] + e3 * lsh[3][qr];
    float inv = 1.f / L;
#pragma unroll
    for (int i = 0; i < 8; ++i) {
      int h = h8 + i;
      float v = e0 * obuf[0][qr][h] + e1 * obuf[1][qr][h] +
                e2 * obuf[2][qr][h] + e3 * obuf[3][qr][h];
      out[(bT + q0 + qr) * NH + h] = v * inv;
    }
  }
}

extern "C" void kernel_launch(void* const* d_in, const int* in_sizes, int n_in,
                              void* d_out, int out_size, void* d_ws, size_t ws_size,
                              hipStream_t stream) {
  const float* x  = (const float*)d_in[0];
  const float* Wq = (const float*)d_in[1];
  const float* Wk = (const float*)d_in[2];
  const float* Wv = (const float*)d_in[3];
  float* out = (float*)d_out;

  char* ws = (char*)d_ws;
  __bf16* wt = (__bf16*)(ws);                        // 384 KB
  __bf16* qb = (__bf16*)(ws + 393216);               // 2 MB
  __bf16* kb = (__bf16*)(ws + 393216 + 2097152);     // 2 MB
  __bf16* vt = (__bf16*)(ws + 393216 + 2 * 2097152); // 2 MB

  wt_kernel<<<dim3(48), dim3(256), 0, stream>>>(Wq, Wk, Wv, wt);
  qkv_mfma_kernel<<<dim3(512), dim3(256), 0, stream>>>(x, wt, qb, kb, vt);
  attn_mfma_kernel<<<dim3(64, 8), dim3(256), 0, stream>>>(qb, kb, vt, out);
}